// Round 9
// baseline (116.073 us; speedup 1.0000x reference)
//
#include <hip/hip_runtime.h>
#include <hip/hip_cooperative_groups.h>
#include <math.h>

// KAN dense layer, MI355X. N_IN=N_OUT=128, K=3, G=8, BATCH=512.
// v9: v7/v8 within noise (67/68us) -> controllable share is launches, not
//     kernel math. Fuse v8's pack + GEMM into ONE cooperative kernel:
//     phase A: dedup'd W-pack (16K thr) + A-pack (64K thr) to global bf16;
//     grid.sync(); phase B: pure fragment-fed 16x16x32 GEMM (v8, proven).
//     Fallback to the v8 two-kernel path if cooperative launch is refused.
#define N_IN  128
#define N_OUT 128
#define BATCH 512
#define NK    11
#define TBV   16
#define TOV   16
#define KTOT  1536           // 128 * 12 (11 spline slots + 1 silu/cres slot)

namespace cg = cooperative_groups;

typedef float f32x4  __attribute__((ext_vector_type(4)));
typedef short bf16x8 __attribute__((ext_vector_type(8)));
typedef unsigned long long u64;

__device__ __forceinline__ unsigned short f2bf(float f) {   // RNE fp32->bf16
    unsigned u = __float_as_uint(f);
    u += 0x7FFFu + ((u >> 16) & 1u);
    return (unsigned short)(u >> 16);
}

// ---- shared phase-A helpers ----
__device__ __forceinline__ void pack_w_one(
    int e, const float* __restrict__ cbasis, const float* __restrict__ cspl,
    const float* __restrict__ cres, unsigned short* __restrict__ w2)
{
    const float s = cspl[e];
    const float* src = cbasis + (size_t)e * NK;
    unsigned short h[12];
    #pragma unroll
    for (int g = 0; g < NK; ++g) h[g] = f2bf(s * src[g]);
    h[11] = f2bf(cres[e]);
    unsigned d[6];
    #pragma unroll
    for (int j = 0; j < 6; ++j)
        d[j] = (unsigned)h[2 * j] | ((unsigned)h[2 * j + 1] << 16);
    unsigned short* dst = w2 + (size_t)e * 12;
    *(uint2*)(dst)     = make_uint2(d[0], d[1]);
    *(uint2*)(dst + 4) = make_uint2(d[2], d[3]);
    *(uint2*)(dst + 8) = make_uint2(d[4], d[5]);
}

__device__ __forceinline__ void pack_a_one(
    int p, const float* __restrict__ x, unsigned short* __restrict__ a2)
{
    const float v = x[p];                                 // coalesced
    const float u = (v + 1.75f) * 4.0f;                   // u in [3,11)
    float jf = floorf(u);
    jf = fminf(fmaxf(jf, 3.0f), 10.0f);
    const float tt = u - jf;
    const float omt = 1.0f - tt;
    const float t2 = tt * tt, t3 = t2 * tt;
    const float B0 = omt * omt * omt * (1.0f / 6.0f);
    const float B1 = (3.0f * t3 - 6.0f * t2 + 4.0f) * (1.0f / 6.0f);
    const float B2 = (-3.0f * t3 + 3.0f * t2 + 3.0f * tt + 1.0f) * (1.0f / 6.0f);
    const float B3 = t3 * (1.0f / 6.0f);
    const int base = (int)jf - 3;                         // 0..7
    const float sig = 1.0f / (1.0f + __expf(-v));
    const u64 v4 = (u64)f2bf(B0) | ((u64)f2bf(B1) << 16)
                 | ((u64)f2bf(B2) << 32) | ((u64)f2bf(B3) << 48);
    const int sh = base * 16;                             // 0..112
    u64 q0, q1, q2;
    if (sh < 64) {
        q0 = v4 << sh;
        q1 = sh ? (v4 >> (64 - sh)) : 0ull;
        q2 = 0ull;
    } else {
        q0 = 0ull;
        q1 = v4 << (sh - 64);
        q2 = (sh > 64) ? (v4 >> (128 - sh)) : 0ull;
    }
    q2 |= (u64)f2bf(v * sig) << 48;                       // silu -> slot 11
    u64* dst = (u64*)(a2 + (size_t)p * 12);               // 8B-aligned, 24B/thr
    dst[0] = q0; dst[1] = q1; dst[2] = q2;
}

// ---- phase-B GEMM body (v8, proven) ----
__device__ __forceinline__ void gemm_tile(
    int b0, int o0, int t,
    const unsigned short* __restrict__ a2, const unsigned short* __restrict__ w2,
    const float* __restrict__ bias, float* __restrict__ y, float* sAcc)
{
    const int w  = t >> 6;                    // wave 0..7: owns K [192w,192w+192)
    const int l  = t & 63;
    const int mn = l & 15;                    // MFMA row (m for A, n for B)
    const int kq = (l >> 4) * 8;              // k sub-offset within 32-k step

    const unsigned short* ab = a2 + (size_t)(b0 + mn) * KTOT + w * 192 + kq;
    const unsigned short* wb = w2 + (size_t)(o0 + mn) * KTOT + w * 192 + kq;
    bf16x8 af[6], wf[6];
    #pragma unroll
    for (int s = 0; s < 6; ++s) {
        af[s] = *(const bf16x8*)(ab + s * 32);   // global_load_dwordx4
        wf[s] = *(const bf16x8*)(wb + s * 32);
    }
    f32x4 acc = {0.f, 0.f, 0.f, 0.f};
    #pragma unroll
    for (int s = 0; s < 6; ++s)
        acc = __builtin_amdgcn_mfma_f32_16x16x32_bf16(af[s], wf[s], acc, 0, 0, 0);

    // reduce 8 wave-partials; C layout: col=lane&15, row=(lane>>4)*4+r
    #pragma unroll
    for (int r = 0; r < 4; ++r)
        sAcc[w * 256 + ((l >> 4) * 4 + r) * 16 + mn] = acc[r];
    __syncthreads();
    if (t < 256) {
        const int m2 = t >> 4, n2 = t & 15;
        float sum = bias[o0 + n2];
        #pragma unroll
        for (int ww = 0; ww < 8; ++ww) sum += sAcc[ww * 256 + t];
        y[(b0 + m2) * N_OUT + (o0 + n2)] = sum;
    }
}

// ---- v9: single cooperative kernel ----
__global__ __launch_bounds__(512) void kan_fused(
    const float* __restrict__ x,      const float* __restrict__ cbasis,
    const float* __restrict__ cspl,   const float* __restrict__ cres,
    const float* __restrict__ bias,   unsigned short* __restrict__ w2,
    unsigned short* __restrict__ a2,  float* __restrict__ y)
{
    __shared__ float sAcc[8 * 256];           // 8 KB: co-residency trivially ok
    const int t   = threadIdx.x;
    const int gid = blockIdx.x * 512 + t;     // 0..131071

    // Phase A: dedup'd packing (each element written exactly once)
    if (gid < 16384) {
        pack_w_one(gid, cbasis, cspl, cres, w2);
    } else if (gid < 16384 + 65536) {
        pack_a_one(gid - 16384, x, a2);
    }

    cg::this_grid().sync();                   // device-scope barrier + fence

    // Phase B: 32 b-tiles x 8 o-tiles
    const int b0 = (blockIdx.x & 31) * TBV;
    const int o0 = (blockIdx.x >> 5) * TOV;
    gemm_tile(b0, o0, t, a2, w2, bias, y, sAcc);
}

// ---- v8 fallback path (identical math) ----
__global__ __launch_bounds__(256) void pack_kernel(
    const float* __restrict__ x,      const float* __restrict__ cbasis,
    const float* __restrict__ cspl,   const float* __restrict__ cres,
    unsigned short* __restrict__ w2,  unsigned short* __restrict__ a2)
{
    if (blockIdx.x < 64) {
        pack_w_one(blockIdx.x * 256 + threadIdx.x, cbasis, cspl, cres, w2);
    } else {
        pack_a_one((blockIdx.x - 64) * 256 + threadIdx.x, x, a2);
    }
}

__global__ __launch_bounds__(512) void kan_kernel(
    const unsigned short* __restrict__ a2, const unsigned short* __restrict__ w2,
    const float* __restrict__ bias, float* __restrict__ y)
{
    __shared__ float sAcc[8 * 256];
    gemm_tile(blockIdx.x * TBV, blockIdx.y * TOV, threadIdx.x,
              a2, w2, bias, y, sAcc);
}

extern "C" void kernel_launch(void* const* d_in, const int* in_sizes, int n_in,
                              void* d_out, int out_size, void* d_ws, size_t ws_size,
                              hipStream_t stream) {
    const float* x      = (const float*)d_in[0];
    // d_in[1] = knots: unused — uniform grid known in closed form
    const float* cbasis = (const float*)d_in[2];
    const float* cspl   = (const float*)d_in[3];
    const float* cres   = (const float*)d_in[4];
    const float* bias   = (const float*)d_in[5];
    float* y = (float*)d_out;
    unsigned short* w2 = (unsigned short*)d_ws;                       // 384 KB
    unsigned short* a2 = (unsigned short*)((char*)d_ws + 512 * 1024); // 1.5 MB

    void* args[] = { (void*)&x, (void*)&cbasis, (void*)&cspl, (void*)&cres,
                     (void*)&bias, (void*)&w2, (void*)&a2, (void*)&y };
    hipError_t err = hipLaunchCooperativeKernel((const void*)kan_fused,
                                                dim3(256), dim3(512),
                                                args, 0, stream);
    if (err != hipSuccess) {
        // graph-capture or platform refused cooperative launch: v8 path
        pack_kernel<<<320, 256, 0, stream>>>(x, cbasis, cspl, cres, w2, a2);
        dim3 grid(BATCH / TBV, N_OUT / TOV);
        kan_kernel<<<grid, 512, 0, stream>>>(a2, w2, bias, y);
    }
}

// Round 10
// 67.228 us; speedup vs baseline: 1.7266x; 1.7266x over previous
//
#include <hip/hip_runtime.h>
#include <math.h>

// KAN dense layer, MI355X. N_IN=N_OUT=128, K=3, G=8, BATCH=512.
// v10 = v7 verbatim (best measured: 67.0 us). Session findings:
//   - uniform grid => closed-form cubic B-spline (no knots read, 4 nonzero)
//   - densified bf16 MFMA GEMM (K=1536 strips) beats all gather variants
//   - w_pack hoisted once; kan: A-slab in LDS + reg-prefetched W frags
//   - 512 thr (2 waves/SIMD) > 256 thr (1 wave/SIMD): latency overlap
//   - falsified: dwordx4 gather repack (v3), LDS c_basis gather (v4, 3x worse),
//     dedup A-pack to global (v8, neutral), cooperative fuse (v9, +48us)
//   - residual ~10us = 2 launch quanta + drain vs ~56us harness fixed floor
#define N_IN  128
#define N_OUT 128
#define BATCH 512
#define NK    11
#define TBV   16
#define TOV   16
#define KTOT  1536           // 128 * 12
#define ASTR  1544           // shorts per A LDS row (1536 + 8 pad)

typedef float f32x4  __attribute__((ext_vector_type(4)));
typedef short bf16x8 __attribute__((ext_vector_type(8)));
typedef unsigned long long u64;

__device__ __forceinline__ unsigned short f2bf(float f) {   // RNE fp32->bf16
    unsigned u = __float_as_uint(f);
    u += 0x7FFFu + ((u >> 16) & 1u);
    return (unsigned short)(u >> 16);
}

// W[o][i*12+g] = cspl[e]*cbasis[e][g] (g<11), slot 11 = cres[e]; e = o*128+i.
__global__ __launch_bounds__(128) void w_pack(
    const float* __restrict__ cbasis, const float* __restrict__ cspl,
    const float* __restrict__ cres, unsigned short* __restrict__ w2)
{
    const int e = blockIdx.x * 128 + threadIdx.x;    // 0..16383
    const float s = cspl[e];
    const float* src = cbasis + (size_t)e * NK;
    unsigned short h[12];
    #pragma unroll
    for (int g = 0; g < NK; ++g) h[g] = f2bf(s * src[g]);
    h[11] = f2bf(cres[e]);
    unsigned d[6];
    #pragma unroll
    for (int j = 0; j < 6; ++j)
        d[j] = (unsigned)h[2 * j] | ((unsigned)h[2 * j + 1] << 16);
    unsigned short* dst = w2 + (size_t)e * 12;
    *(uint2*)(dst)     = make_uint2(d[0], d[1]);
    *(uint2*)(dst + 4) = make_uint2(d[2], d[3]);
    *(uint2*)(dst + 8) = make_uint2(d[4], d[5]);
}

__global__ __launch_bounds__(512) void kan_kernel(
    const float* __restrict__ x,              // [512][128]
    const unsigned short* __restrict__ w2,    // [128][1536] bf16 packed
    const float* __restrict__ bias,           // [128]
    float* __restrict__ y)                    // [512][128]
{
    __shared__ short sA[TBV * ASTR];          // 49,408 B
    __shared__ float sAcc[8 * 256];           //  8,192 B

    const int b0 = blockIdx.x * TBV;          // 32 blocks in x
    const int o0 = blockIdx.y * TOV;          // 8 blocks in y
    const int t  = threadIdx.x;
    const int w  = t >> 6;                    // wave 0..7: owns K [192w,192w+192)
    const int l  = t & 63;
    const int mn = l & 15;                    // MFMA row (m for A, n for B)
    const int kq = (l >> 4) * 8;              // k sub-offset within 32-k step

    // ---- prefetch this wave's 6 W fragments (latency hidden by A-build) ----
    const unsigned short* wb = w2 + (size_t)(o0 + mn) * KTOT + w * 192 + kq;
    bf16x8 wf[6];
    #pragma unroll
    for (int s = 0; s < 6; ++s)
        wf[s] = *(const bf16x8*)(wb + s * 32);   // global_load_dwordx4

    // ---- build A slab: 16 b x 128 i, 4 per thread ----
    float xv[4];
    #pragma unroll
    for (int it = 0; it < 4; ++it) {          // hoist x loads: one vmcnt wait
        const int p = t + it * 512;
        xv[it] = x[(b0 + (p >> 7)) * N_IN + (p & 127)];
    }
    #pragma unroll
    for (int it = 0; it < 4; ++it) {
        const int p = t + it * 512;
        const int b = p >> 7, i = p & 127;
        const float v = xv[it];
        const float u = (v + 1.75f) * 4.0f;              // u in [3,11)
        float jf = floorf(u);
        jf = fminf(fmaxf(jf, 3.0f), 10.0f);
        const float tt = u - jf;
        const float omt = 1.0f - tt;
        const float t2 = tt * tt, t3 = t2 * tt;
        const float B0 = omt * omt * omt * (1.0f / 6.0f);
        const float B1 = (3.0f * t3 - 6.0f * t2 + 4.0f) * (1.0f / 6.0f);
        const float B2 = (-3.0f * t3 + 3.0f * t2 + 3.0f * tt + 1.0f) * (1.0f / 6.0f);
        const float B3 = t3 * (1.0f / 6.0f);
        const int base = (int)jf - 3;                    // 0..7
        const float sig = 1.0f / (1.0f + __expf(-v));
        // 4 bf16 -> u64, placed at bit offset base*16 in the 192-bit strip
        const u64 v4 = (u64)f2bf(B0) | ((u64)f2bf(B1) << 16)
                     | ((u64)f2bf(B2) << 32) | ((u64)f2bf(B3) << 48);
        const int sh = base * 16;                        // 0..112
        u64 q0, q1, q2;
        if (sh < 64) {
            q0 = v4 << sh;
            q1 = sh ? (v4 >> (64 - sh)) : 0ull;
            q2 = 0ull;
        } else {
            q0 = 0ull;
            q1 = v4 << (sh - 64);
            q2 = (sh > 64) ? (v4 >> (128 - sh)) : 0ull;
        }
        q2 |= (u64)f2bf(v * sig) << 48;                  // silu -> slot 11
        u64* dst = (u64*)&sA[b * ASTR + i * 12];         // 8B-aligned
        dst[0] = q0; dst[1] = q1; dst[2] = q2;
    }
    __syncthreads();

    // ---- MFMA: 6 steps of 16x16x32 over this wave's K range ----
    f32x4 acc = {0.f, 0.f, 0.f, 0.f};
    const short* aB = &sA[mn * ASTR + w * 192 + kq];     // 16B-aligned
    #pragma unroll
    for (int s = 0; s < 6; ++s) {
        bf16x8 af = *(const bf16x8*)(aB + s * 32);       // ds_read_b128
        acc = __builtin_amdgcn_mfma_f32_16x16x32_bf16(af, wf[s], acc, 0, 0, 0);
    }

    // ---- reduce 8 wave-partials; C layout: col=lane&15, row=(lane>>4)*4+r ----
    #pragma unroll
    for (int r = 0; r < 4; ++r)
        sAcc[w * 256 + ((l >> 4) * 4 + r) * 16 + mn] = acc[r];
    __syncthreads();
    if (t < 256) {
        const int m2 = t >> 4, n2 = t & 15;
        float sum = bias[o0 + n2];
        #pragma unroll
        for (int ww = 0; ww < 8; ++ww) sum += sAcc[ww * 256 + t];
        y[(b0 + m2) * N_OUT + (o0 + n2)] = sum;
    }
}

extern "C" void kernel_launch(void* const* d_in, const int* in_sizes, int n_in,
                              void* d_out, int out_size, void* d_ws, size_t ws_size,
                              hipStream_t stream) {
    const float* x      = (const float*)d_in[0];
    // d_in[1] = knots: unused — uniform grid known in closed form
    const float* cbasis = (const float*)d_in[2];
    const float* cspl   = (const float*)d_in[3];
    const float* cres   = (const float*)d_in[4];
    const float* bias   = (const float*)d_in[5];
    float* y = (float*)d_out;
    unsigned short* w2 = (unsigned short*)d_ws;   // 384 KB scratch

    w_pack<<<128, 128, 0, stream>>>(cbasis, cspl, cres, w2);
    dim3 grid(BATCH / TBV, N_OUT / TOV);          // 32 x 8 = 256 blocks, 1/CU
    kan_kernel<<<grid, 512, 0, stream>>>(x, w2, bias, y);
}